// Round 5
// baseline (145.071 us; speedup 1.0000x reference)
//
#include <hip/hip_runtime.h>
#include <hip/hip_bf16.h>

#define NV 100000
#define ND 64
#define NB 4096
#define NL 200
#define MT 13        // m-tiles of 16 rows -> 208 (200 real + 8 zero pad)

typedef __bf16 bf16_t;
typedef __bf16 bf16x8 __attribute__((ext_vector_type(8)));
typedef __bf16 bf16x4 __attribute__((ext_vector_type(4)));
typedef float f32x4 __attribute__((ext_vector_type(4)));

#define TB_ELEMS ((long)NV * ND)      // bf16 shadow emb table elems (12.8 MB)
#define TBV (TB_ELEMS / 8)            // 800000 vector cvt tasks
#define FT1 (128 * 192)               // fW1T elems (B-frag layout [n][k])
#define FT2 (64 * 128)                // fW2T elems
#define AWT (64 * 192)                // awT elems: awT[n][k] = aW1[k][n], bf16
#define CVT_TASKS (TBV + FT1 + FT2 + AWT)

// ---- kernel 0: f32->bf16 emb table + transposed bf16 weights ----
__global__ __launch_bounds__(256)
void cvt_kernel(const float* __restrict__ emb,
                const float* __restrict__ aW1,
                const float* __restrict__ fW1,
                const float* __restrict__ fW2,
                bf16_t* __restrict__ tb,
                bf16_t* __restrict__ fW1T,
                bf16_t* __restrict__ fW2T,
                bf16_t* __restrict__ awT)
{
    long t = (long)blockIdx.x * 256 + threadIdx.x;
    if (t >= CVT_TASKS) return;
    if (t < TBV) {
        long i = t * 8;
        f32x4 a0 = *(const f32x4*)(emb + i);
        f32x4 a1 = *(const f32x4*)(emb + i + 4);
        bf16x8 o;
#pragma unroll
        for (int j = 0; j < 4; ++j) { o[j] = (bf16_t)a0[j]; o[j + 4] = (bf16_t)a1[j]; }
        *(bf16x8*)(tb + i) = o;
    } else {
        int u = (int)(t - TBV);
        if (u < FT1) {                     // fW1T[n][k] = fW1[k][n]
            int n = u / 192, k = u - n * 192;
            fW1T[u] = (bf16_t)fW1[k * 128 + n];
        } else if (u < FT1 + FT2) {        // fW2T[n][k] = fW2[k][n]
            int u2 = u - FT1;
            int n = u2 >> 7, k = u2 & 127;
            fW2T[u2] = (bf16_t)fW2[k * 64 + n];
        } else {                           // awT[n][k] = aW1[k][n], k<192
            int u3 = u - FT1 - FT2;
            int n = u3 / 192, k = u3 - n * 192;
            awT[u3] = (bf16_t)aW1[k * 64 + n];
        }
    }
}

// Fused DIN, 2 batch rows / block (512 thr). Chain-trimmed version:
//  - biases folded into MFMA C-init (phase 3, fc1, fc2)
//  - phase 2 reads pre-transposed bf16 awT (3 b128 loads vs 24 f32)
//  - one-pass softmax (wave-local e + per-wave (m_w,s_w)); pool applies
//    exp(m_w-m)*rtot with a compile-time scale index (l>>6 == j>>2)
//  - 8 barriers (was 9)
// LDS 78144 B -> 2 blocks/CU.
__global__ __launch_bounds__(512, 4)
void din_kernel1(const int* __restrict__ item_ids,
                 const int* __restrict__ history,
                 const int* __restrict__ hist_len,
                 const float* __restrict__ emb,
                 const bf16_t* __restrict__ tb,
                 const bf16_t* __restrict__ awT,
                 const float* __restrict__ ab1,
                 const float* __restrict__ aW2,
                 const bf16_t* __restrict__ fW1T, const float* __restrict__ fb1,
                 const bf16_t* __restrict__ fW2T, const float* __restrict__ fb2,
                 const float* __restrict__ fW3, const float* __restrict__ fb3,
                 float* __restrict__ out)
{
    __shared__ __align__(16) bf16_t histA[2][208 * 64];   // 53248 B
    __shared__ __align__(16) bf16_t wbT[2][64 * 64];      // 16384 B, wbT[n][k]
    __shared__ float tgt[2][64];
    __shared__ __align__(16) float scores[2][208];
    __shared__ float wts[2][208];
    __shared__ float pp2[2][512];
    __shared__ float red[2][8];
    __shared__ float cb2[2][64];

    // MLP tiles alias wbT (dead after phase 3)
    bf16_t* comb16 = (bf16_t*)wbT;                  // [16][200] bf16, 6400 B
    bf16_t* z1s    = (bf16_t*)wbT + 3200;           // [16][136] bf16, 4352 B
    float*  z2f    = (float*)((bf16_t*)wbT + 5376); // [2][64] f32,    512 B

    const int b0  = blockIdx.x * 2;
    const int tid = threadIdx.x;
    const int len0 = hist_len[b0];
    const int len1 = hist_len[b0 + 1];

    if (tid < 128) {
        int bx = tid >> 6, d = tid & 63;
        tgt[bx][d] = emb[(long)item_ids[b0 + bx] * ND + d];
    }

    // ---- phase 1: gather 2x208 rows from bf16 table (all loads first) ----
    {
        const int p = tid & 1;        // half-row: 32 bf16 = 64 B
        const int s = tid >> 1;       // 0..255
        const int bxA = (s >= 208);
        const int lA  = s - bxA * 208;
        const int lB  = s + 48;
        const int lenA = bxA ? len1 : len0;
        const bool vB = (s < 160);
        const bf16x8 z = (bf16x8)(bf16_t)0.f;
        bf16x8 a0 = z, a1 = z, a2 = z, a3 = z;
        bf16x8 c0 = z, c1 = z, c2 = z, c3 = z;
        if (lA < lenA) {
            const bf16_t* src = tb + (long)history[(long)(b0 + bxA) * NL + lA] * ND + p * 32;
            a0 = *(const bf16x8*)(src);
            a1 = *(const bf16x8*)(src + 8);
            a2 = *(const bf16x8*)(src + 16);
            a3 = *(const bf16x8*)(src + 24);
        }
        if (vB && lB < len1) {
            const bf16_t* src = tb + (long)history[(long)(b0 + 1) * NL + lB] * ND + p * 32;
            c0 = *(const bf16x8*)(src);
            c1 = *(const bf16x8*)(src + 8);
            c2 = *(const bf16x8*)(src + 16);
            c3 = *(const bf16x8*)(src + 24);
        }
        {
            bf16_t* d = &histA[bxA][lA * 64];
            const int S = (lA & 7) << 3;
            *(bf16x8*)&d[(p * 32 +  0) ^ S] = a0;
            *(bf16x8*)&d[(p * 32 +  8) ^ S] = a1;
            *(bf16x8*)&d[(p * 32 + 16) ^ S] = a2;
            *(bf16x8*)&d[(p * 32 + 24) ^ S] = a3;
        }
        if (vB) {
            bf16_t* d = &histA[1][lB * 64];
            const int S = (lB & 7) << 3;
            *(bf16x8*)&d[(p * 32 +  0) ^ S] = c0;
            *(bf16x8*)&d[(p * 32 +  8) ^ S] = c1;
            *(bf16x8*)&d[(p * 32 + 16) ^ S] = c2;
            *(bf16x8*)&d[(p * 32 + 24) ^ S] = c3;
        }
    }

    // ---- phase 2: Wb^T for BOTH rows from one pass over bf16 awT ----
    {
        const int n  = tid & 63;
        const int kp = tid >> 6;      // 0..7 -> k = kp*8 + i
        const long t0 = (long)item_ids[b0] * ND;
        const long t1 = (long)item_ids[b0 + 1] * ND;
        f32x4 tk0a = *(const f32x4*)(emb + t0 + kp * 8);
        f32x4 tk0b = *(const f32x4*)(emb + t0 + kp * 8 + 4);
        f32x4 tk1a = *(const f32x4*)(emb + t1 + kp * 8);
        f32x4 tk1b = *(const f32x4*)(emb + t1 + kp * 8 + 4);
        bf16x8 va = *(const bf16x8*)&awT[n * 192 + kp * 8];         // hist part
        bf16x8 vm = *(const bf16x8*)&awT[n * 192 + 64 + kp * 8];    // mid part
        bf16x8 vp = *(const bf16x8*)&awT[n * 192 + 128 + kp * 8];   // prod part
        float cs0 = 0.f, cs1 = 0.f;
        bf16x8 w0v, w1v;
#pragma unroll
        for (int i = 0; i < 8; ++i) {
            float tk0 = (i < 4) ? tk0a[i] : tk0b[i - 4];
            float tk1 = (i < 4) ? tk1a[i] : tk1b[i - 4];
            float ah = (float)va[i];
            float am = (float)vm[i];
            float ap = (float)vp[i];
            w0v[i] = (bf16_t)(ah + tk0 * ap);
            w1v[i] = (bf16_t)(ah + tk1 * ap);
            cs0 += tk0 * am;
            cs1 += tk1 * am;
        }
        const int S = (n & 7) << 3;
        *(bf16x8*)&wbT[0][n * 64 + ((kp * 8) ^ S)] = w0v;
        *(bf16x8*)&wbT[1][n * 64 + ((kp * 8) ^ S)] = w1v;
        pp2[0][kp * 64 + n] = cs0;
        pp2[1][kp * 64 + n] = cs1;
    }
    __syncthreads();   // B1

    // cb2[bx][n] = ab1[n] + sum_k tgt_k * aW1_mid[k][n]
    if (tid < 128) {
        const int bx = tid >> 6, n = tid & 63;
        float s = ab1[n];
#pragma unroll
        for (int kp = 0; kp < 8; ++kp) s += pp2[bx][kp * 64 + n];
        cb2[bx][n] = s;
    }
    __syncthreads();   // B2

    // ---- phase 3: S^T = Wb^T @ hist^T via MFMA (bias in C-init) ----
    {
        const int wave = tid >> 6;
        const int lane = tid & 63;
        const int bx   = wave & 1;
        const int col  = lane & 15;
        const int quad = lane >> 4;

        bf16x8 afrag[4][2];
#pragma unroll
        for (int nt = 0; nt < 4; ++nt) {
            const int n = nt * 16 + col;
            const int S = (n & 7) << 3;
#pragma unroll
            for (int kb = 0; kb < 2; ++kb)
                afrag[nt][kb] = *(const bf16x8*)&wbT[bx][n * 64 + ((kb * 32 + quad * 8) ^ S)];
        }
        float cv[4][4], a2[4][4];
#pragma unroll
        for (int nt = 0; nt < 4; ++nt)
#pragma unroll
            for (int i = 0; i < 4; ++i) {
                const int no = nt * 16 + quad * 4 + i;
                cv[nt][i] = cb2[bx][no];
                a2[nt][i] = aW2[no];
            }

        for (int mt = (wave >> 1); mt < MT; mt += 4) {
            const int l = mt * 16 + col;     // B-operand n = l
            const int S = (l & 7) << 3;
            const bf16_t* base = &histA[bx][l * 64];
            bf16x8 bf0 = *(const bf16x8*)&base[(     quad * 8) ^ S];
            bf16x8 bf1 = *(const bf16x8*)&base[(32 + quad * 8) ^ S];
            float sc = 0.f;
#pragma unroll
            for (int nt = 0; nt < 4; ++nt) {
                f32x4 acc = {cv[nt][0], cv[nt][1], cv[nt][2], cv[nt][3]};
                acc = __builtin_amdgcn_mfma_f32_16x16x32_bf16(afrag[nt][0], bf0, acc, 0, 0, 0);
                acc = __builtin_amdgcn_mfma_f32_16x16x32_bf16(afrag[nt][1], bf1, acc, 0, 0, 0);
#pragma unroll
                for (int i = 0; i < 4; ++i) {
                    float h = acc[i] > 0.f ? acc[i] : 0.f;
                    sc += h * a2[nt][i];
                }
            }
            sc += __shfl_xor(sc, 16, 64);
            sc += __shfl_xor(sc, 32, 64);
            if (quad == 0) scores[bx][mt * 16 + col] = sc;
        }
    }
    __syncthreads();   // B3

    // ---- phase 4: one-pass softmax (wave-local e; publish m_w, s_w) ----
    {
        const int bx = tid >> 8, t = tid & 255;
        float s = (t < NL) ? scores[bx][t] : -1e30f;
        float m = s;
        for (int off = 32; off > 0; off >>= 1) m = fmaxf(m, __shfl_xor(m, off, 64));
        float e = (t < NL) ? __expf(s - m) : 0.f;     // local to wave max
        if (t < NL) wts[bx][t] = e;
        else if (t < 208) wts[bx][t] = 0.f;           // zero pad for phase 5
        float ss = e;
        for (int off = 32; off > 0; off >>= 1) ss += __shfl_xor(ss, off, 64);
        if ((t & 63) == 0) { red[bx][t >> 6] = m; red[bx][4 + (t >> 6)] = ss; }
    }
    __syncthreads();   // B4

    // ---- phase 5: pooled partials; rescale by exp(m_w-m)*rtot inline ----
    // l = g + 16j with g<16  =>  l>>6 == j>>2 (compile-time scale select)
    {
        const int bx = tid >> 8, t = tid & 255;
        const int c = t & 15;         // d = c*4 .. c*4+3
        const int g = t >> 4;         // 0..15 row-groups
        const int w4 = (tid >> 6) & 3;
        const float m0 = red[bx][0], m1 = red[bx][1], m2 = red[bx][2], m3 = red[bx][3];
        const float mg = fmaxf(fmaxf(m0, m1), fmaxf(m2, m3));
        float sc0 = __expf(m0 - mg), sc1 = __expf(m1 - mg);
        float sc2 = __expf(m2 - mg), sc3 = __expf(m3 - mg);
        const float rtot = 1.f / (sc0 * red[bx][4] + sc1 * red[bx][5] +
                                  sc2 * red[bx][6] + sc3 * red[bx][7]);
        sc0 *= rtot; sc1 *= rtot; sc2 *= rtot; sc3 *= rtot;
        f32x4 acc = {0.f, 0.f, 0.f, 0.f};
#pragma unroll
        for (int j = 0; j < 13; ++j) {
            const int l = g + j * 16;
            const float scj = (j < 4) ? sc0 : (j < 8) ? sc1 : (j < 12) ? sc2 : sc3;
            const float wl = wts[bx][l] * scj;
            bf16x4 v = *(const bf16x4*)&histA[bx][l * 64 + ((c * 4) ^ ((l & 7) << 3))];
#pragma unroll
            for (int k = 0; k < 4; ++k) acc[k] += wl * (float)v[k];
        }
#pragma unroll
        for (int k = 0; k < 4; ++k) {
            acc[k] += __shfl_xor(acc[k], 16, 64);
            acc[k] += __shfl_xor(acc[k], 32, 64);
        }
        if ((tid & 63) < 16) *(f32x4*)&pp2[bx][w4 * 64 + c * 4] = acc;
    }

    // prefetch MLP weights to registers (global, L2-hot)
    bf16x8 bw1[6]; float b1v;
    bf16x8 bw2[4]; float b2v = 0.f;
    {
        const int wave = tid >> 6, lane = tid & 63;
        const int col = lane & 15, quad = lane >> 4;
        const int n = wave * 16 + col;          // 0..127
#pragma unroll
        for (int ks = 0; ks < 6; ++ks)
            bw1[ks] = *(const bf16x8*)&fW1T[(long)n * 192 + ks * 32 + quad * 8];
        b1v = fb1[n];
        if (wave < 4) {
            const int n2 = wave * 16 + col;     // 0..63
#pragma unroll
            for (int ks = 0; ks < 4; ++ks)
                bw2[ks] = *(const bf16x8*)&fW2T[(long)n2 * 128 + ks * 32 + quad * 8];
            b2v = fb2[n2];
        }
    }
    __syncthreads();   // B5

    // ---- phase 6: comb16 tile (rows 0-1 = b0,b1; rows 2-15 zero) ----
    {
        const int bx = tid >> 8, t = tid & 255;
        if (t < 192) {
            const int d = t & 63;
            float v;
            if (t < 64) v = tgt[bx][d];
            else {
                float pl = pp2[bx][d] + pp2[bx][64 + d] + pp2[bx][128 + d] + pp2[bx][192 + d];
                v = (t < 128) ? pl : pl - tgt[bx][d];
            }
            comb16[bx * 200 + t] = (bf16_t)v;
        }
        if (tid >= 384) {
            const bf16x8 z = (bf16x8)(bf16_t)0.f;
            const int u = tid - 384;
#pragma unroll
            for (int s = u; s < 350; s += 128) *(bf16x8*)&comb16[400 + s * 8] = z;
        }
    }
    __syncthreads();   // B6

    // ---- phase 7: z1 = relu(comb @ fW1 + fb1) via MFMA [192->128] ----
    {
        const int wave = tid >> 6, lane = tid & 63;   // wave = nt (8 tiles)
        const int col = lane & 15, quad = lane >> 4;
        f32x4 acc = {b1v, b1v, b1v, b1v};
#pragma unroll
        for (int ks = 0; ks < 6; ++ks) {
            bf16x8 a = *(const bf16x8*)&comb16[col * 200 + ks * 32 + quad * 8];
            acc = __builtin_amdgcn_mfma_f32_16x16x32_bf16(a, bw1[ks], acc, 0, 0, 0);
        }
        const int n = wave * 16 + col;
#pragma unroll
        for (int i = 0; i < 4; ++i) {
            const int m = quad * 4 + i;
            float zv = (m < 2) ? fmaxf(acc[i], 0.f) : 0.f;
            z1s[m * 136 + n] = (bf16_t)zv;
        }
    }
    __syncthreads();   // B7

    // ---- phase 8: z2 = relu(z1 @ fW2 + fb2) via MFMA [128->64] ----
    {
        const int wave = tid >> 6, lane = tid & 63;
        const int col = lane & 15, quad = lane >> 4;
        if (wave < 4) {
            f32x4 acc = {b2v, b2v, b2v, b2v};
#pragma unroll
            for (int ks = 0; ks < 4; ++ks) {
                bf16x8 a = *(const bf16x8*)&z1s[col * 136 + ks * 32 + quad * 8];
                acc = __builtin_amdgcn_mfma_f32_16x16x32_bf16(a, bw2[ks], acc, 0, 0, 0);
            }
            const int n2 = wave * 16 + col;
#pragma unroll
            for (int i = 0; i < 4; ++i) {
                const int m = quad * 4 + i;
                if (m < 2) z2f[m * 64 + n2] = fmaxf(acc[i], 0.f);
            }
        }
    }
    __syncthreads();   // B8

    // ---- phase 9: out = sigmoid(z2 . fW3 + fb3) ----
    if (tid < 128) {
        const int bx = tid >> 6, j = tid & 63;
        float s = z2f[bx * 64 + j] * fW3[j];
        for (int off = 32; off > 0; off >>= 1) s += __shfl_xor(s, off, 64);
        if (j == 0) out[b0 + bx] = 1.f / (1.f + __expf(-(s + fb3[0])));
    }
}

extern "C" void kernel_launch(void* const* d_in, const int* in_sizes, int n_in,
                              void* d_out, int out_size, void* d_ws, size_t ws_size,
                              hipStream_t stream) {
    const int*   item_ids = (const int*)d_in[0];
    const int*   history  = (const int*)d_in[1];
    const int*   hist_len = (const int*)d_in[2];
    const float* emb      = (const float*)d_in[3];
    const float* aW1      = (const float*)d_in[4];
    const float* ab1      = (const float*)d_in[5];
    const float* aW2      = (const float*)d_in[6];
    // d_in[7] = ab2: softmax is shift-invariant, exactly cancels -> unused
    const float* fW1      = (const float*)d_in[8];
    const float* fb1      = (const float*)d_in[9];
    const float* fW2      = (const float*)d_in[10];
    const float* fb2      = (const float*)d_in[11];
    const float* fW3      = (const float*)d_in[12];
    const float* fb3      = (const float*)d_in[13];

    // ws layout: bf16 [emb table | fW1T | fW2T | awT], contiguous, 16B-aligned
    bf16_t* tb   = (bf16_t*)d_ws;
    bf16_t* fW1T = tb + TB_ELEMS;
    bf16_t* fW2T = fW1T + FT1;
    bf16_t* awTp = fW2T + FT2;

    cvt_kernel<<<(int)((CVT_TASKS + 255) / 256), 256, 0, stream>>>(
        emb, aW1, fW1, fW2, tb, fW1T, fW2T, awTp);
    din_kernel1<<<NB / 2, 512, 0, stream>>>(item_ids, history, hist_len, emb, tb,
                                            awTp, ab1, aW2,
                                            fW1T, fb1, fW2T, fb2, fW3, fb3,
                                            (float*)d_out);
}